// Round 14
// baseline (163.376 us; speedup 1.0000x reference)
//
#include <hip/hip_runtime.h>
#include <hip/hip_bf16.h>
#include <math.h>

#define BATCH 16384
#define NF 26
#define ND 13
#define VOC 100000
#define KP0 448
#define KP1 416
#define CS 80    // cols per N-slice
#define NSL 5    // N-slices (5*80 = 400 real cols)
#define NGB 4096 // gather blocks (first in grid)

typedef __bf16 bf16x8 __attribute__((ext_vector_type(8)));
typedef float f32x4 __attribute__((ext_vector_type(4)));
using bf16 = __hip_bfloat16;
typedef unsigned short u16;

__device__ __forceinline__ void gload_lds16(const void* g, void* l) {
  __builtin_amdgcn_global_load_lds(
      (const __attribute__((address_space(1))) void*)g,
      (__attribute__((address_space(3))) void*)l, 16, 0, 0);
}

__device__ __forceinline__ u16 f2bu(float v) {
  union { __hip_bfloat16 b; u16 u; } cv;
  cv.b = __float2bfloat16(v);
  return cv.u;
}

// ---------- merged: vectorized gather/FM + weight transpose (R12-verbatim) ----------
__global__ __launch_bounds__(256) void prep_gather_kernel(
    const float* __restrict__ w0, const float* __restrict__ w1,
    const float* __restrict__ w2, bf16* __restrict__ wt0,
    bf16* __restrict__ wt1, bf16* __restrict__ wt2,
    const int* __restrict__ xs, const float* __restrict__ xd,
    const float* __restrict__ emb1, const float* __restrict__ emb2,
    const float* __restrict__ wd, const float* __restrict__ biasp,
    bf16* __restrict__ h0, float* __restrict__ partial) {
  const int bid = blockIdx.x, tid = threadIdx.x;
  if (bid >= NGB) {  // ---- prep
    const int pbid = bid - NGB;
    const float* W; bf16* Wt; int K, KP, idx;
    if (pbid < 728)       { W = w0; Wt = wt0; K = 429; KP = KP0; idx = pbid * 256 + tid; }
    else if (pbid < 1404) { W = w1; Wt = wt1; K = 400; KP = KP1; idx = (pbid - 728) * 256 + tid; }
    else                  { W = w2; Wt = wt2; K = 400; KP = KP1; idx = (pbid - 1404) * 256 + tid; }
    int k = idx % KP, n = idx / KP;
    float v = (k < K && n < 400) ? W[(size_t)k * 400 + n] : 0.f;
    Wt[idx] = __float2bfloat16(v);
    return;
  }
  const int p = bid;
  const int x8 = p & 7, qb = p >> 3;
  const int gl = (qb >> 5) * 256 + x8 * 32 + (qb & 31);
  const int w = tid >> 6, lane = tid & 63;
  const int b = gl * 4 + w;
  const int q = lane >> 2, sub = lane & 3;

  int xsl = 0;
  if (lane < NF) xsl = xs[b * NF + lane];
  float lin = 0.f;
  if (lane < NF) lin = emb1[(size_t)lane * VOC + xsl];
  if (lane < ND) lin += xd[b * ND + lane] * wd[lane];

  float4 sv = make_float4(0.f, 0.f, 0.f, 0.f);
  float sq = 0.f;
#pragma unroll
  for (int i = 0; i < 2; ++i) {
    int f = i * 16 + q;
    if (f < NF) {
      int idx = __shfl(xsl, f);
      float4 v = *((const float4*)(emb2 + ((size_t)f * VOC + idx) * 16) + sub);
      sv.x += v.x; sv.y += v.y; sv.z += v.z; sv.w += v.w;
      sq += v.x * v.x + v.y * v.y + v.z * v.z + v.w * v.w;
      ushort4 st;
      st.x = f2bu(v.x); st.y = f2bu(v.y); st.z = f2bu(v.z); st.w = f2bu(v.w);
      *(ushort4*)(h0 + (size_t)b * KP0 + f * 16 + sub * 4) = st;
    }
  }
  if (lane < 32) {
    float v = (lane < ND) ? xd[b * ND + lane] : 0.f;
    h0[(size_t)b * KP0 + 416 + lane] = __float2bfloat16(v);
  }
#pragma unroll
  for (int off = 4; off < 64; off <<= 1) {
    sv.x += __shfl_xor(sv.x, off);
    sv.y += __shfl_xor(sv.y, off);
    sv.z += __shfl_xor(sv.z, off);
    sv.w += __shfl_xor(sv.w, off);
  }
  float t = sv.x * sv.x + sv.y * sv.y + sv.z * sv.z + sv.w * sv.w;
#pragma unroll
  for (int off = 1; off < 64; off <<= 1) {
    t += __shfl_xor(t, off);
    sq += __shfl_xor(sq, off);
    lin += __shfl_xor(lin, off);
  }
  if (lane == 0)
    partial[b] = biasp[0] + lin + 0.5f * (t * 0.0625f - sq);
}

// ---------- W-stationary streaming GEMM (R12-verbatim) ----------
template <int NK, bool FINAL>
__global__ __launch_bounds__(256, 2) void gemm_kernel(
    const bf16* __restrict__ A, const bf16* __restrict__ Wt,
    const float* __restrict__ bias, bf16* __restrict__ outH,
    const float* __restrict__ fw, float* __restrict__ dotb) {
  constexpr int KP = NK * 32;
  extern __shared__ __align__(16) char smem[];
  const int b = blockIdx.x, tid = threadIdx.x;
  const int w = tid >> 6, lane = tid & 63, r = lane & 15, g = lane >> 4;
  const int lane8 = b & 7, hi = b >> 3;
  const int s = hi % NSL, mchunk = (hi / NSL) * 8 + lane8;
  const int row0 = mchunk * 128, col0 = s * CS;

  {
    const char* wbase = (const char*)(Wt + (size_t)col0 * KP);
    constexpr int T = NK * CS * 4;
    constexpr int FULL = T >> 8, REM = T & 255;
    for (int rd = 0; rd <= FULL; ++rd) {
      if (rd < FULL || tid < REM) {
        int c = rd * 256 + tid;
        int kk = c / (CS * 4), rm = c - kk * (CS * 4);
        int n = rm >> 2, j = rm & 3;
        int kc = j ^ ((n >> 1) & 3);
        gload_lds16(wbase + (size_t)n * (KP * 2) + kk * 64 + kc * 16,
                    smem + (rd * 256 + w * 64) * 16);
      }
    }
  }
  __syncthreads();

  const char* Ab = (const char*)(A + (size_t)(row0 + w * 32 + r) * KP) + g * 16;
  const size_t rtS = (size_t)16 * KP * 2;

  f32x4 acc[2][NSL];
#pragma unroll
  for (int rt = 0; rt < 2; ++rt)
#pragma unroll
    for (int ct = 0; ct < NSL; ++ct) acc[rt][ct] = (f32x4){0.f, 0.f, 0.f, 0.f};

  const int swz = ((g ^ ((r >> 1) & 3)) << 4);
  for (int k = 0; k < NK; ++k) {
    bf16x8 a0 = *(const bf16x8*)(Ab + k * 64);
    bf16x8 a1 = *(const bf16x8*)(Ab + k * 64 + rtS);
    const char* sb = smem + k * (CS * 64) + r * 64 + swz;
#pragma unroll
    for (int ct = 0; ct < NSL; ++ct) {
      bf16x8 bfr = *(const bf16x8*)(sb + ct * 1024);
      acc[0][ct] = __builtin_amdgcn_mfma_f32_16x16x32_bf16(a0, bfr, acc[0][ct], 0, 0, 0);
      acc[1][ct] = __builtin_amdgcn_mfma_f32_16x16x32_bf16(a1, bfr, acc[1][ct], 0, 0, 0);
    }
  }

  if (!FINAL) {
#pragma unroll
    for (int ct = 0; ct < NSL; ++ct) {
      int col = col0 + ct * 16 + r;
      float bv = bias[col];
#pragma unroll
      for (int rt = 0; rt < 2; ++rt)
#pragma unroll
        for (int q = 0; q < 4; ++q) {
          float v = fmaxf(acc[rt][ct][q] + bv, 0.f);
          outH[(size_t)(row0 + w * 32 + rt * 16 + g * 4 + q) * KP1 + col] =
              __float2bfloat16(v);
        }
    }
  } else {
    float pr[2][4] = {{0.f, 0.f, 0.f, 0.f}, {0.f, 0.f, 0.f, 0.f}};
#pragma unroll
    for (int ct = 0; ct < NSL; ++ct) {
      int col = col0 + ct * 16 + r;
      float bv = bias[col], fv = fw[col];
#pragma unroll
      for (int rt = 0; rt < 2; ++rt)
#pragma unroll
        for (int q = 0; q < 4; ++q)
          pr[rt][q] += fmaxf(acc[rt][ct][q] + bv, 0.f) * fv;
    }
#pragma unroll
    for (int rt = 0; rt < 2; ++rt)
#pragma unroll
      for (int q = 0; q < 4; ++q) {
        pr[rt][q] += __shfl_xor(pr[rt][q], 1);
        pr[rt][q] += __shfl_xor(pr[rt][q], 2);
        pr[rt][q] += __shfl_xor(pr[rt][q], 4);
        pr[rt][q] += __shfl_xor(pr[rt][q], 8);
      }
    if (r < 4) {
#pragma unroll
      for (int rt = 0; rt < 2; ++rt) {
        float v = (r == 0) ? pr[rt][0] : (r == 1) ? pr[rt][1]
                : (r == 2) ? pr[rt][2] : pr[rt][3];
        dotb[(size_t)s * BATCH + row0 + w * 32 + rt * 16 + g * 4 + r] = v;
      }
    }
  }
}

// ---------- combine 5 slice partials + sigmoid (R12-verbatim) ----------
__global__ void finish_kernel(const float* __restrict__ partial,
                              const float* __restrict__ dotb,
                              float* __restrict__ out) {
  int i = blockIdx.x * 256 + threadIdx.x;
  if (i < BATCH) {
    float x = partial[i] + dotb[i] + dotb[BATCH + i] + dotb[2 * BATCH + i]
            + dotb[3 * BATCH + i] + dotb[4 * BATCH + i];
    out[i] = 1.f / (1.f + expf(-x));
  }
}

extern "C" void kernel_launch(void* const* d_in, const int* in_sizes, int n_in,
                              void* d_out, int out_size, void* d_ws, size_t ws_size,
                              hipStream_t stream) {
  const int* xs = (const int*)d_in[0];
  const float* xd = (const float*)d_in[1];
  const float* emb1 = (const float*)d_in[2];
  const float* emb2 = (const float*)d_in[3];
  const float* wd = (const float*)d_in[4];
  const float* bias = (const float*)d_in[5];
  const float* w0 = (const float*)d_in[6];
  const float* b0 = (const float*)d_in[7];
  const float* w1 = (const float*)d_in[8];
  const float* b1 = (const float*)d_in[9];
  const float* w2 = (const float*)d_in[10];
  const float* b2 = (const float*)d_in[11];
  const float* fw = (const float*)d_in[12];
  float* out = (float*)d_out;

  char* ws = (char*)d_ws;
  float* partial = (float*)(ws + 0);        //  65536 B
  float* dotb    = (float*)(ws + 65536);    // 327680 B
  bf16* wt0 = (bf16*)(ws + 393216);         // 372736
  bf16* wt1 = (bf16*)(ws + 765952);         // 346112
  bf16* wt2 = (bf16*)(ws + 1112064);        // 346112 -> 1458176
  bf16* h0  = (bf16*)(ws + 1458176);        // 14680064
  bf16* h1  = (bf16*)(ws + 16138240);       // 13631488
  bf16* h2  = (bf16*)(ws + 29769728);       // 13631488

  constexpr int LDS14 = 14 * CS * 64;       // 71680
  constexpr int LDS13 = 13 * CS * 64;       // 66560
  hipFuncSetAttribute((const void*)gemm_kernel<14, false>,
                      hipFuncAttributeMaxDynamicSharedMemorySize, LDS14);
  hipFuncSetAttribute((const void*)gemm_kernel<13, false>,
                      hipFuncAttributeMaxDynamicSharedMemorySize, LDS13);
  hipFuncSetAttribute((const void*)gemm_kernel<13, true>,
                      hipFuncAttributeMaxDynamicSharedMemorySize, LDS13);

  prep_gather_kernel<<<NGB + 2080, 256, 0, stream>>>(
      w0, w1, w2, wt0, wt1, wt2, xs, xd, emb1, emb2, wd, bias, h0, partial);

  // DIAGNOSTIC: GEMM chain replayed 3x (idempotent -> bitwise-identical output).
  // dur_delta vs R12 = 2 x (T_gemm0 + T_gemm1 + T_gemm2 + 3 boundaries).
  for (int rep = 0; rep < 3; ++rep) {
    gemm_kernel<14, false><<<640, 256, LDS14, stream>>>(h0, wt0, b0, h1, nullptr, nullptr);
    gemm_kernel<13, false><<<640, 256, LDS13, stream>>>(h1, wt1, b1, h2, nullptr, nullptr);
    gemm_kernel<13, true><<<640, 256, LDS13, stream>>>(h2, wt2, b2, nullptr, fw, dotb);
  }

  finish_kernel<<<64, 256, 0, stream>>>(partial, dotb, out);
}

// Round 15
// 70.780 us; speedup vs baseline: 2.3082x; 2.3082x over previous
//
#include <hip/hip_runtime.h>
#include <hip/hip_bf16.h>
#include <math.h>

#define BATCH 16384
#define NF 26
#define ND 13
#define VOC 100000
#define KP0 448
#define KP1 416
#define CS 80    // cols per N-slice
#define NSL 5    // N-slices (5*80 = 400 real cols)
#define NGB 4096 // gather blocks (first in grid)

typedef __bf16 bf16x8 __attribute__((ext_vector_type(8)));
typedef float f32x4 __attribute__((ext_vector_type(4)));
using bf16 = __hip_bfloat16;
typedef unsigned short u16;

__device__ __forceinline__ void gload_lds16(const void* g, void* l) {
  __builtin_amdgcn_global_load_lds(
      (const __attribute__((address_space(1))) void*)g,
      (__attribute__((address_space(3))) void*)l, 16, 0, 0);
}

__device__ __forceinline__ u16 f2bu(float v) {
  union { __hip_bfloat16 b; u16 u; } cv;
  cv.b = __float2bfloat16(v);
  return cv.u;
}

// ---------- merged: vectorized gather/FM + weight transpose (R12-verbatim) ----------
__global__ __launch_bounds__(256) void prep_gather_kernel(
    const float* __restrict__ w0, const float* __restrict__ w1,
    const float* __restrict__ w2, bf16* __restrict__ wt0,
    bf16* __restrict__ wt1, bf16* __restrict__ wt2,
    const int* __restrict__ xs, const float* __restrict__ xd,
    const float* __restrict__ emb1, const float* __restrict__ emb2,
    const float* __restrict__ wd, const float* __restrict__ biasp,
    bf16* __restrict__ h0, float* __restrict__ partial) {
  const int bid = blockIdx.x, tid = threadIdx.x;
  if (bid >= NGB) {  // ---- prep
    const int pbid = bid - NGB;
    const float* W; bf16* Wt; int K, KP, idx;
    if (pbid < 728)       { W = w0; Wt = wt0; K = 429; KP = KP0; idx = pbid * 256 + tid; }
    else if (pbid < 1404) { W = w1; Wt = wt1; K = 400; KP = KP1; idx = (pbid - 728) * 256 + tid; }
    else                  { W = w2; Wt = wt2; K = 400; KP = KP1; idx = (pbid - 1404) * 256 + tid; }
    int k = idx % KP, n = idx / KP;
    float v = (k < K && n < 400) ? W[(size_t)k * 400 + n] : 0.f;
    Wt[idx] = __float2bfloat16(v);
    return;
  }
  const int p = bid;
  const int x8 = p & 7, qb = p >> 3;
  const int gl = (qb >> 5) * 256 + x8 * 32 + (qb & 31);
  const int w = tid >> 6, lane = tid & 63;
  const int b = gl * 4 + w;
  const int q = lane >> 2, sub = lane & 3;

  int xsl = 0;
  if (lane < NF) xsl = xs[b * NF + lane];
  float lin = 0.f;
  if (lane < NF) lin = emb1[(size_t)lane * VOC + xsl];
  if (lane < ND) lin += xd[b * ND + lane] * wd[lane];

  float4 sv = make_float4(0.f, 0.f, 0.f, 0.f);
  float sq = 0.f;
#pragma unroll
  for (int i = 0; i < 2; ++i) {
    int f = i * 16 + q;
    if (f < NF) {
      int idx = __shfl(xsl, f);
      float4 v = *((const float4*)(emb2 + ((size_t)f * VOC + idx) * 16) + sub);
      sv.x += v.x; sv.y += v.y; sv.z += v.z; sv.w += v.w;
      sq += v.x * v.x + v.y * v.y + v.z * v.z + v.w * v.w;
      ushort4 st;
      st.x = f2bu(v.x); st.y = f2bu(v.y); st.z = f2bu(v.z); st.w = f2bu(v.w);
      *(ushort4*)(h0 + (size_t)b * KP0 + f * 16 + sub * 4) = st;
    }
  }
  if (lane < 32) {
    float v = (lane < ND) ? xd[b * ND + lane] : 0.f;
    h0[(size_t)b * KP0 + 416 + lane] = __float2bfloat16(v);
  }
#pragma unroll
  for (int off = 4; off < 64; off <<= 1) {
    sv.x += __shfl_xor(sv.x, off);
    sv.y += __shfl_xor(sv.y, off);
    sv.z += __shfl_xor(sv.z, off);
    sv.w += __shfl_xor(sv.w, off);
  }
  float t = sv.x * sv.x + sv.y * sv.y + sv.z * sv.z + sv.w * sv.w;
#pragma unroll
  for (int off = 1; off < 64; off <<= 1) {
    t += __shfl_xor(t, off);
    sq += __shfl_xor(sq, off);
    lin += __shfl_xor(lin, off);
  }
  if (lane == 0)
    partial[b] = biasp[0] + lin + 0.5f * (t * 0.0625f - sq);
}

// ---------- W-stationary streaming GEMM ----------
// R15 change vs R12: ALL A-fragments are loaded to registers at kernel entry,
// BEFORE the W staging loads -- their L2 latency overlaps the stage+barrier.
// The k-loop is then pure LDS+MFMA with compile-time register indexing.
template <int NK, bool FINAL>
__global__ __launch_bounds__(256, 2) void gemm_kernel(
    const bf16* __restrict__ A, const bf16* __restrict__ Wt,
    const float* __restrict__ bias, bf16* __restrict__ outH,
    const float* __restrict__ fw, float* __restrict__ dotb) {
  constexpr int KP = NK * 32;
  extern __shared__ __align__(16) char smem[];
  const int b = blockIdx.x, tid = threadIdx.x;
  const int w = tid >> 6, lane = tid & 63, r = lane & 15, g = lane >> 4;
  const int lane8 = b & 7, hi = b >> 3;
  const int s = hi % NSL, mchunk = (hi / NSL) * 8 + lane8;
  const int row0 = mchunk * 128, col0 = s * CS;

  // ---- issue ALL A-fragment loads first (hoisted out of the k-loop)
  const char* Ab = (const char*)(A + (size_t)(row0 + w * 32 + r) * KP) + g * 16;
  const size_t rtS = (size_t)16 * KP * 2;
  bf16x8 a0[NK], a1[NK];
#pragma unroll
  for (int k = 0; k < NK; ++k) {
    a0[k] = *(const bf16x8*)(Ab + k * 64);
    a1[k] = *(const bf16x8*)(Ab + k * 64 + rtS);
  }

  // ---- stage W-slice (R12-verbatim)
  {
    const char* wbase = (const char*)(Wt + (size_t)col0 * KP);
    constexpr int T = NK * CS * 4;
    constexpr int FULL = T >> 8, REM = T & 255;
    for (int rd = 0; rd <= FULL; ++rd) {
      if (rd < FULL || tid < REM) {
        int c = rd * 256 + tid;
        int kk = c / (CS * 4), rm = c - kk * (CS * 4);
        int n = rm >> 2, j = rm & 3;
        int kc = j ^ ((n >> 1) & 3);
        gload_lds16(wbase + (size_t)n * (KP * 2) + kk * 64 + kc * 16,
                    smem + (rd * 256 + w * 64) * 16);
      }
    }
  }
  __syncthreads();

  f32x4 acc[2][NSL];
#pragma unroll
  for (int rt = 0; rt < 2; ++rt)
#pragma unroll
    for (int ct = 0; ct < NSL; ++ct) acc[rt][ct] = (f32x4){0.f, 0.f, 0.f, 0.f};

  const int swz = ((g ^ ((r >> 1) & 3)) << 4);
#pragma unroll
  for (int k = 0; k < NK; ++k) {
    const char* sb = smem + k * (CS * 64) + r * 64 + swz;
#pragma unroll
    for (int ct = 0; ct < NSL; ++ct) {
      bf16x8 bfr = *(const bf16x8*)(sb + ct * 1024);
      acc[0][ct] = __builtin_amdgcn_mfma_f32_16x16x32_bf16(a0[k], bfr, acc[0][ct], 0, 0, 0);
      acc[1][ct] = __builtin_amdgcn_mfma_f32_16x16x32_bf16(a1[k], bfr, acc[1][ct], 0, 0, 0);
    }
  }

  if (!FINAL) {
#pragma unroll
    for (int ct = 0; ct < NSL; ++ct) {
      int col = col0 + ct * 16 + r;
      float bv = bias[col];
#pragma unroll
      for (int rt = 0; rt < 2; ++rt)
#pragma unroll
        for (int q = 0; q < 4; ++q) {
          float v = fmaxf(acc[rt][ct][q] + bv, 0.f);
          outH[(size_t)(row0 + w * 32 + rt * 16 + g * 4 + q) * KP1 + col] =
              __float2bfloat16(v);
        }
    }
  } else {
    float pr[2][4] = {{0.f, 0.f, 0.f, 0.f}, {0.f, 0.f, 0.f, 0.f}};
#pragma unroll
    for (int ct = 0; ct < NSL; ++ct) {
      int col = col0 + ct * 16 + r;
      float bv = bias[col], fv = fw[col];
#pragma unroll
      for (int rt = 0; rt < 2; ++rt)
#pragma unroll
        for (int q = 0; q < 4; ++q)
          pr[rt][q] += fmaxf(acc[rt][ct][q] + bv, 0.f) * fv;
    }
#pragma unroll
    for (int rt = 0; rt < 2; ++rt)
#pragma unroll
      for (int q = 0; q < 4; ++q) {
        pr[rt][q] += __shfl_xor(pr[rt][q], 1);
        pr[rt][q] += __shfl_xor(pr[rt][q], 2);
        pr[rt][q] += __shfl_xor(pr[rt][q], 4);
        pr[rt][q] += __shfl_xor(pr[rt][q], 8);
      }
    if (r < 4) {
#pragma unroll
      for (int rt = 0; rt < 2; ++rt) {
        float v = (r == 0) ? pr[rt][0] : (r == 1) ? pr[rt][1]
                : (r == 2) ? pr[rt][2] : pr[rt][3];
        dotb[(size_t)s * BATCH + row0 + w * 32 + rt * 16 + g * 4 + r] = v;
      }
    }
  }
}

// ---------- combine 5 slice partials + sigmoid (R12-verbatim) ----------
__global__ void finish_kernel(const float* __restrict__ partial,
                              const float* __restrict__ dotb,
                              float* __restrict__ out) {
  int i = blockIdx.x * 256 + threadIdx.x;
  if (i < BATCH) {
    float x = partial[i] + dotb[i] + dotb[BATCH + i] + dotb[2 * BATCH + i]
            + dotb[3 * BATCH + i] + dotb[4 * BATCH + i];
    out[i] = 1.f / (1.f + expf(-x));
  }
}

extern "C" void kernel_launch(void* const* d_in, const int* in_sizes, int n_in,
                              void* d_out, int out_size, void* d_ws, size_t ws_size,
                              hipStream_t stream) {
  const int* xs = (const int*)d_in[0];
  const float* xd = (const float*)d_in[1];
  const float* emb1 = (const float*)d_in[2];
  const float* emb2 = (const float*)d_in[3];
  const float* wd = (const float*)d_in[4];
  const float* bias = (const float*)d_in[5];
  const float* w0 = (const float*)d_in[6];
  const float* b0 = (const float*)d_in[7];
  const float* w1 = (const float*)d_in[8];
  const float* b1 = (const float*)d_in[9];
  const float* w2 = (const float*)d_in[10];
  const float* b2 = (const float*)d_in[11];
  const float* fw = (const float*)d_in[12];
  float* out = (float*)d_out;

  char* ws = (char*)d_ws;
  float* partial = (float*)(ws + 0);        //  65536 B
  float* dotb    = (float*)(ws + 65536);    // 327680 B
  bf16* wt0 = (bf16*)(ws + 393216);         // 372736
  bf16* wt1 = (bf16*)(ws + 765952);         // 346112
  bf16* wt2 = (bf16*)(ws + 1112064);        // 346112 -> 1458176
  bf16* h0  = (bf16*)(ws + 1458176);        // 14680064
  bf16* h1  = (bf16*)(ws + 16138240);       // 13631488
  bf16* h2  = (bf16*)(ws + 29769728);       // 13631488

  constexpr int LDS14 = 14 * CS * 64;       // 71680
  constexpr int LDS13 = 13 * CS * 64;       // 66560
  hipFuncSetAttribute((const void*)gemm_kernel<14, false>,
                      hipFuncAttributeMaxDynamicSharedMemorySize, LDS14);
  hipFuncSetAttribute((const void*)gemm_kernel<13, false>,
                      hipFuncAttributeMaxDynamicSharedMemorySize, LDS13);
  hipFuncSetAttribute((const void*)gemm_kernel<13, true>,
                      hipFuncAttributeMaxDynamicSharedMemorySize, LDS13);

  prep_gather_kernel<<<NGB + 2080, 256, 0, stream>>>(
      w0, w1, w2, wt0, wt1, wt2, xs, xd, emb1, emb2, wd, bias, h0, partial);

  gemm_kernel<14, false><<<640, 256, LDS14, stream>>>(h0, wt0, b0, h1, nullptr, nullptr);
  gemm_kernel<13, false><<<640, 256, LDS13, stream>>>(h1, wt1, b1, h2, nullptr, nullptr);
  gemm_kernel<13, true><<<640, 256, LDS13, stream>>>(h2, wt2, b2, nullptr, fw, dotb);

  finish_kernel<<<64, 256, 0, stream>>>(partial, dotb, out);
}

// Round 16
// 64.751 us; speedup vs baseline: 2.5232x; 1.0931x over previous
//
#include <hip/hip_runtime.h>
#include <hip/hip_bf16.h>
#include <math.h>

#define BATCH 16384
#define NF 26
#define ND 13
#define VOC 100000
#define KP0 448
#define KP1 416
#define CS 112   // cols per N-slice (7 tiles)
#define NSL 4    // N-slices (4*112 = 448 >= 400, pad cols zero)
#define NGB 4096 // gather blocks (first in grid)
#define NPB 2240 // prep blocks (after gather)

typedef __bf16 bf16x8 __attribute__((ext_vector_type(8)));
typedef float f32x4 __attribute__((ext_vector_type(4)));
using bf16 = __hip_bfloat16;
typedef unsigned short u16;

__device__ __forceinline__ void gload_lds16(const void* g, void* l) {
  __builtin_amdgcn_global_load_lds(
      (const __attribute__((address_space(1))) void*)g,
      (__attribute__((address_space(3))) void*)l, 16, 0, 0);
}

__device__ __forceinline__ u16 f2bu(float v) {
  union { __hip_bfloat16 b; u16 u; } cv;
  cv.b = __float2bfloat16(v);
  return cv.u;
}

// ---------- merged: vectorized gather/FM (bid < NGB) + weight transpose
// (bid >= NGB; wt cols padded to 448) ----------
__global__ __launch_bounds__(256) void prep_gather_kernel(
    const float* __restrict__ w0, const float* __restrict__ w1,
    const float* __restrict__ w2, bf16* __restrict__ wt0,
    bf16* __restrict__ wt1, bf16* __restrict__ wt2,
    const int* __restrict__ xs, const float* __restrict__ xd,
    const float* __restrict__ emb1, const float* __restrict__ emb2,
    const float* __restrict__ wd, const float* __restrict__ biasp,
    bf16* __restrict__ h0, float* __restrict__ partial) {
  const int bid = blockIdx.x, tid = threadIdx.x;
  if (bid >= NGB) {  // ---- prep: Wt[n][k], n < 448 (pad n>=400 and k>=K zero)
    const int pbid = bid - NGB;
    const float* W; bf16* Wt; int K, KP, idx;
    if (pbid < 784)       { W = w0; Wt = wt0; K = 429; KP = KP0; idx = pbid * 256 + tid; }
    else if (pbid < 1512) { W = w1; Wt = wt1; K = 400; KP = KP1; idx = (pbid - 784) * 256 + tid; }
    else                  { W = w2; Wt = wt2; K = 400; KP = KP1; idx = (pbid - 1512) * 256 + tid; }
    int k = idx % KP, n = idx / KP;
    float v = (k < K && n < 400) ? W[(size_t)k * 400 + n] : 0.f;
    Wt[idx] = __float2bfloat16(v);
    return;
  }
  // ---- gather + FM, one wave per sample, float4-vectorized (proven body)
  const int p = bid;
  const int x8 = p & 7, qb = p >> 3;
  const int gl = (qb >> 5) * 256 + x8 * 32 + (qb & 31);
  const int w = tid >> 6, lane = tid & 63;
  const int b = gl * 4 + w;
  const int q = lane >> 2, sub = lane & 3;

  int xsl = 0;
  if (lane < NF) xsl = xs[b * NF + lane];
  float lin = 0.f;
  if (lane < NF) lin = emb1[(size_t)lane * VOC + xsl];
  if (lane < ND) lin += xd[b * ND + lane] * wd[lane];

  float4 sv = make_float4(0.f, 0.f, 0.f, 0.f);
  float sq = 0.f;
#pragma unroll
  for (int i = 0; i < 2; ++i) {
    int f = i * 16 + q;
    if (f < NF) {
      int idx = __shfl(xsl, f);
      float4 v = *((const float4*)(emb2 + ((size_t)f * VOC + idx) * 16) + sub);
      sv.x += v.x; sv.y += v.y; sv.z += v.z; sv.w += v.w;
      sq += v.x * v.x + v.y * v.y + v.z * v.z + v.w * v.w;
      ushort4 st;
      st.x = f2bu(v.x); st.y = f2bu(v.y); st.z = f2bu(v.z); st.w = f2bu(v.w);
      *(ushort4*)(h0 + (size_t)b * KP0 + f * 16 + sub * 4) = st;
    }
  }
  if (lane < 32) {
    float v = (lane < ND) ? xd[b * ND + lane] : 0.f;
    h0[(size_t)b * KP0 + 416 + lane] = __float2bfloat16(v);
  }
#pragma unroll
  for (int off = 4; off < 64; off <<= 1) {
    sv.x += __shfl_xor(sv.x, off);
    sv.y += __shfl_xor(sv.y, off);
    sv.z += __shfl_xor(sv.z, off);
    sv.w += __shfl_xor(sv.w, off);
  }
  float t = sv.x * sv.x + sv.y * sv.y + sv.z * sv.z + sv.w * sv.w;
#pragma unroll
  for (int off = 1; off < 64; off <<= 1) {
    t += __shfl_xor(t, off);
    sq += __shfl_xor(sq, off);
    lin += __shfl_xor(lin, off);
  }
  if (lane == 0)
    partial[b] = biasp[0] + lin + 0.5f * (t * 0.0625f - sq);
}

// ---------- W-stationary GEMM, grid 512 = 128 mchunks x 4 slices (one
// residency wave at 2 blocks/CU). W staged in TWO K-phases through a single
// 50 KB LDS buffer; A frags register-hoisted per phase (phase-1 issued early,
// hidden under phase-0 compute). ----------
template <int NK, bool FINAL>
__global__ __launch_bounds__(256, 2) void gemm_kernel(
    const bf16* __restrict__ A, const bf16* __restrict__ Wt,
    const float* __restrict__ bias, bf16* __restrict__ outH,
    const float* __restrict__ fw, float* __restrict__ dotb) {
  constexpr int KP = NK * 32;
  constexpr int NKB = NK - 7;           // phase-1 k-steps (7 or 6)
  extern __shared__ __align__(16) char smem[];
  const int b = blockIdx.x, tid = threadIdx.x;
  const int w = tid >> 6, lane = tid & 63, r = lane & 15, g = lane >> 4;
  const int lane8 = b & 7, hi = b >> 3;
  const int s = hi & 3, mchunk = (hi >> 2) * 8 + lane8;
  const int row0 = mchunk * 128, col0 = s * CS;
  const char* wbase = (const char*)(Wt + (size_t)col0 * KP);

  // stage k-steps [kbase, kbase+nks) into the (single) LDS buffer
  auto stageP = [&](int kbase, int chunks) {
    for (int c0 = 0; c0 < chunks; c0 += 256) {
      int c = c0 + tid;
      if (c < chunks) {                  // remainders are x64 -> wave-uniform
        int kk = c / (CS * 4);
        int rm = c - kk * (CS * 4);
        int n = rm >> 2, j = rm & 3;
        int kc = j ^ ((n >> 1) & 3);
        gload_lds16(wbase + (size_t)n * (KP * 2) + (kbase + kk) * 64 + kc * 16,
                    smem + (c0 + w * 64) * 16);
      }
    }
  };

  const char* Ab = (const char*)(A + (size_t)(row0 + w * 32 + r) * KP) + g * 16;
  const size_t rtS = (size_t)16 * KP * 2;

  // ---- phase-0 A frags, then stage phase-0 W
  bf16x8 aA0[7], aA1[7];
#pragma unroll
  for (int k = 0; k < 7; ++k) {
    aA0[k] = *(const bf16x8*)(Ab + k * 64);
    aA1[k] = *(const bf16x8*)(Ab + k * 64 + rtS);
  }
  stageP(0, 7 * CS * 4);
  __syncthreads();

  // ---- phase-1 A frags issued now (latency hides under phase-0 compute)
  bf16x8 aB0[NKB], aB1[NKB];
#pragma unroll
  for (int k = 0; k < NKB; ++k) {
    aB0[k] = *(const bf16x8*)(Ab + (7 + k) * 64);
    aB1[k] = *(const bf16x8*)(Ab + (7 + k) * 64 + rtS);
  }

  f32x4 acc[2][7];
#pragma unroll
  for (int rt = 0; rt < 2; ++rt)
#pragma unroll
    for (int ct = 0; ct < 7; ++ct) acc[rt][ct] = (f32x4){0.f, 0.f, 0.f, 0.f};

  const int swz = ((g ^ ((r >> 1) & 3)) << 4);
  // ---- compute phase 0
#pragma unroll
  for (int kk = 0; kk < 7; ++kk) {
    const char* sb = smem + kk * (CS * 64) + r * 64 + swz;
#pragma unroll
    for (int ct = 0; ct < 7; ++ct) {
      bf16x8 bfr = *(const bf16x8*)(sb + ct * 1024);
      acc[0][ct] = __builtin_amdgcn_mfma_f32_16x16x32_bf16(aA0[kk], bfr, acc[0][ct], 0, 0, 0);
      acc[1][ct] = __builtin_amdgcn_mfma_f32_16x16x32_bf16(aA1[kk], bfr, acc[1][ct], 0, 0, 0);
    }
  }
  __syncthreads();                       // all waves done reading buffer
  stageP(7, NKB * CS * 4);
  __syncthreads();                       // stage-1 complete
  // ---- compute phase 1
#pragma unroll
  for (int kk = 0; kk < NKB; ++kk) {
    const char* sb = smem + kk * (CS * 64) + r * 64 + swz;
#pragma unroll
    for (int ct = 0; ct < 7; ++ct) {
      bf16x8 bfr = *(const bf16x8*)(sb + ct * 1024);
      acc[0][ct] = __builtin_amdgcn_mfma_f32_16x16x32_bf16(aB0[kk], bfr, acc[0][ct], 0, 0, 0);
      acc[1][ct] = __builtin_amdgcn_mfma_f32_16x16x32_bf16(aB1[kk], bfr, acc[1][ct], 0, 0, 0);
    }
  }

  if (!FINAL) {
#pragma unroll
    for (int ct = 0; ct < 7; ++ct) {
      int col = col0 + ct * 16 + r;
      if (col < 400) {
        float bv = bias[col];
#pragma unroll
        for (int rt = 0; rt < 2; ++rt)
#pragma unroll
          for (int q = 0; q < 4; ++q) {
            float v = fmaxf(acc[rt][ct][q] + bv, 0.f);
            outH[(size_t)(row0 + w * 32 + rt * 16 + g * 4 + q) * KP1 + col] =
                __float2bfloat16(v);
          }
      }
    }
  } else {
    float pr[2][4] = {{0.f, 0.f, 0.f, 0.f}, {0.f, 0.f, 0.f, 0.f}};
#pragma unroll
    for (int ct = 0; ct < 7; ++ct) {
      int col = col0 + ct * 16 + r;
      if (col < 400) {
        float bv = bias[col], fv = fw[col];
#pragma unroll
        for (int rt = 0; rt < 2; ++rt)
#pragma unroll
          for (int q = 0; q < 4; ++q)
            pr[rt][q] += fmaxf(acc[rt][ct][q] + bv, 0.f) * fv;
      }
    }
#pragma unroll
    for (int rt = 0; rt < 2; ++rt)
#pragma unroll
      for (int q = 0; q < 4; ++q) {
        pr[rt][q] += __shfl_xor(pr[rt][q], 1);
        pr[rt][q] += __shfl_xor(pr[rt][q], 2);
        pr[rt][q] += __shfl_xor(pr[rt][q], 4);
        pr[rt][q] += __shfl_xor(pr[rt][q], 8);
      }
    if (r < 4) {
#pragma unroll
      for (int rt = 0; rt < 2; ++rt) {
        float v = (r == 0) ? pr[rt][0] : (r == 1) ? pr[rt][1]
                : (r == 2) ? pr[rt][2] : pr[rt][3];
        dotb[(size_t)s * BATCH + row0 + w * 32 + rt * 16 + g * 4 + r] = v;
      }
    }
  }
}

// ---------- combine 4 slice partials + sigmoid ----------
__global__ void finish_kernel(const float* __restrict__ partial,
                              const float* __restrict__ dotb,
                              float* __restrict__ out) {
  int i = blockIdx.x * 256 + threadIdx.x;
  if (i < BATCH) {
    float x = partial[i] + dotb[i] + dotb[BATCH + i] + dotb[2 * BATCH + i]
            + dotb[3 * BATCH + i];
    out[i] = 1.f / (1.f + expf(-x));
  }
}

extern "C" void kernel_launch(void* const* d_in, const int* in_sizes, int n_in,
                              void* d_out, int out_size, void* d_ws, size_t ws_size,
                              hipStream_t stream) {
  const int* xs = (const int*)d_in[0];
  const float* xd = (const float*)d_in[1];
  const float* emb1 = (const float*)d_in[2];
  const float* emb2 = (const float*)d_in[3];
  const float* wd = (const float*)d_in[4];
  const float* bias = (const float*)d_in[5];
  const float* w0 = (const float*)d_in[6];
  const float* b0 = (const float*)d_in[7];
  const float* w1 = (const float*)d_in[8];
  const float* b1 = (const float*)d_in[9];
  const float* w2 = (const float*)d_in[10];
  const float* b2 = (const float*)d_in[11];
  const float* fw = (const float*)d_in[12];
  float* out = (float*)d_out;

  char* ws = (char*)d_ws;
  float* partial = (float*)(ws + 0);        //    65536 B
  float* dotb    = (float*)(ws + 65536);    //   262144 B (4 x 16384 f32)
  bf16* wt0 = (bf16*)(ws + 327680);         // 448*448*2 = 401408
  bf16* wt1 = (bf16*)(ws + 729088);         // 448*416*2 = 372736
  bf16* wt2 = (bf16*)(ws + 1101824);        // 372736 -> 1474560
  bf16* h0  = (bf16*)(ws + 1474560);        // 14680064
  bf16* h1  = (bf16*)(ws + 16154624);       // 13631488
  bf16* h2  = (bf16*)(ws + 29786112);       // 13631488

  constexpr int LDSB = 7 * CS * 64;         // 50176 (single phase buffer)
  hipFuncSetAttribute((const void*)gemm_kernel<14, false>,
                      hipFuncAttributeMaxDynamicSharedMemorySize, LDSB);
  hipFuncSetAttribute((const void*)gemm_kernel<13, false>,
                      hipFuncAttributeMaxDynamicSharedMemorySize, LDSB);
  hipFuncSetAttribute((const void*)gemm_kernel<13, true>,
                      hipFuncAttributeMaxDynamicSharedMemorySize, LDSB);

  prep_gather_kernel<<<NGB + NPB, 256, 0, stream>>>(
      w0, w1, w2, wt0, wt1, wt2, xs, xd, emb1, emb2, wd, bias, h0, partial);

  gemm_kernel<14, false><<<512, 256, LDSB, stream>>>(h0, wt0, b0, h1, nullptr, nullptr);
  gemm_kernel<13, false><<<512, 256, LDSB, stream>>>(h1, wt1, b1, h2, nullptr, nullptr);
  gemm_kernel<13, true><<<512, 256, LDSB, stream>>>(h2, wt2, b2, nullptr, fw, dotb);

  finish_kernel<<<64, 256, 0, stream>>>(partial, dotb, out);
}